// Round 2
// baseline (562.065 us; speedup 1.0000x reference)
//
#include <hip/hip_runtime.h>

#define NN 3072
#define NWORD 96   // u32 mask words per row
#define HH 8

typedef short short8 __attribute__((ext_vector_type(8)));
typedef float float4v __attribute__((ext_vector_type(4)));
typedef unsigned short ushort4v __attribute__((ext_vector_type(4)));
typedef unsigned short ushort8v __attribute__((ext_vector_type(8)));

__device__ __forceinline__ float bf2f(unsigned short u) {
  union { unsigned u; float f; } v; v.u = ((unsigned)u) << 16; return v.f;
}
__device__ __forceinline__ unsigned short f2bf(float f) {
  union { float f; unsigned u; } v; v.f = f;
  unsigned r = v.u + 0x7fffu + ((v.u >> 16) & 1u);
  return (unsigned short)(r >> 16);
}
// flag==1 -> buffers are bf16; flag==0 -> fp32
__device__ __forceinline__ float ldin(const void* p, size_t i, int isbf) {
  return isbf ? bf2f(((const unsigned short*)p)[i]) : ((const float*)p)[i];
}

// ---- dtype detect: adj is exactly {0.0,1.0}. fp32 words have low16==0 always;
// bf16 packs two elems/word, ~5% of low halves are 0x3F80. ----
__global__ __launch_bounds__(256) void k_detect(const unsigned* __restrict__ aw,
                                                int* __restrict__ flag) {
  __shared__ int s;
  if (threadIdx.x == 0) s = 0;
  __syncthreads();
  int any = 0;
  for (int i = threadIdx.x; i < 16384; i += 256)
    any |= ((aw[i] & 0xFFFFu) != 0u);
  if (any) s = 1;   // benign race
  __syncthreads();
  if (threadIdx.x == 0) *flag = s;
}

// ---- build bitmask from adj ----
__global__ __launch_bounds__(256) void k_mask(const void* __restrict__ adj,
                                              const int* __restrict__ flag,
                                              unsigned* __restrict__ maskw) {
  int isbf = *flag;
  int row = blockIdx.y;
  int j = blockIdx.x * 256 + threadIdx.x;
  bool pred = ldin(adj, (size_t)row * NN + j, isbf) != 0.f;
  unsigned long long b = __ballot(pred);
  int lane = threadIdx.x & 63;
  int word = row * NWORD + blockIdx.x * 8 + (threadIdx.x >> 6) * 2;
  if (lane == 0) maskw[word] = (unsigned)b;
  else if (lane == 32) maskw[word + 1] = (unsigned)(b >> 32);
}

// ---- mergeState: h = x + (obs==1) * theta ----
__global__ __launch_bounds__(256) void k_merge(const void* __restrict__ x,
                                               const int* __restrict__ obs,
                                               const void* __restrict__ theta,
                                               const int* __restrict__ flag,
                                               unsigned short* __restrict__ h) {
  int isbf = *flag;
  int i = blockIdx.x * 256 + threadIdx.x;
  int row = i >> 8, c = i & 255;
  float v = ldin(x, i, isbf);
  if (obs[row] == 1) v += ldin(theta, c, isbf);
  h[i] = f2bf(v);
}

// ---- batched 16x16 LDS transpose: in[b][R][C] -> out[b][C][R] (out bf16) ----
__global__ __launch_bounds__(256) void k_transpose(const void* __restrict__ in,
                                                   const int* __restrict__ flag,
                                                   unsigned short* __restrict__ out,
                                                   int R, int C) {
  __shared__ __align__(16) unsigned short tile[16][17];
  int isbf = *flag;
  int b = blockIdx.z;
  size_t base = (size_t)b * R * C;
  unsigned short* pout = out + base;
  int r0 = blockIdx.y * 16, c0 = blockIdx.x * 16;
  int tc = threadIdx.x & 15, tr = threadIdx.x >> 4;
  tile[tr][tc] = f2bf(ldin(in, base + (size_t)(r0 + tr) * C + (c0 + tc), isbf));
  __syncthreads();
  pout[(size_t)(c0 + tr) * R + (r0 + tc)] = tile[tc][tr];
}

// ---- GEMM: CT[n][m] = sum_k A[m][k] * WT[n][k], all bf16, M=3072 ----
template<int K, int NCT>
__global__ __launch_bounds__(256) void k_gemm(const unsigned short* __restrict__ A,
                                              const unsigned short* __restrict__ WT,
                                              unsigned short* __restrict__ CT,
                                              long aOff, long wOff, long cOff) {
  int head = blockIdx.y;
  A += (size_t)head * aOff; WT += (size_t)head * wOff; CT += (size_t)head * cOff;
  int rowbase = blockIdx.x * 64;
  int t = threadIdx.x;
  int w = t >> 6, lane = t & 63;
  int q = lane >> 4, l = lane & 15;
  int colbase = w * 16 * NCT;
  float4v acc[4][NCT];
#pragma unroll
  for (int rt = 0; rt < 4; rt++)
#pragma unroll
    for (int ct = 0; ct < NCT; ct++) { float4v z = {0.f, 0.f, 0.f, 0.f}; acc[rt][ct] = z; }

  for (int kb = 0; kb < K; kb += 32) {
    short8 af[4], bfr[NCT];
#pragma unroll
    for (int rt = 0; rt < 4; rt++)
      af[rt] = *(const short8*)(A + (size_t)(rowbase + rt * 16 + l) * K + kb + q * 8);
#pragma unroll
    for (int ct = 0; ct < NCT; ct++)
      bfr[ct] = *(const short8*)(WT + (size_t)(colbase + ct * 16 + l) * K + kb + q * 8);
#pragma unroll
    for (int rt = 0; rt < 4; rt++)
#pragma unroll
      for (int ct = 0; ct < NCT; ct++)
        acc[rt][ct] = __builtin_amdgcn_mfma_f32_16x16x32_bf16(af[rt], bfr[ct], acc[rt][ct], 0, 0, 0);
  }
#pragma unroll
  for (int rt = 0; rt < 4; rt++)
#pragma unroll
    for (int ct = 0; ct < NCT; ct++) {
      int r = rowbase + rt * 16 + q * 4;          // C/D: row = quad*4 + reg
      int n = colbase + ct * 16 + l;              // C/D: col = lane&15
      ushort4v u;
      u.x = f2bf(acc[rt][ct].x); u.y = f2bf(acc[rt][ct].y);
      u.z = f2bf(acc[rt][ct].z); u.w = f2bf(acc[rt][ct].w);
      *(ushort4v*)(CT + (size_t)n * NN + r) = u;
    }
}

// ---- f1/f2 GEMV from WhT: f1[r]=sum_c WhT[c][r]*a[c], f2 with a[DC+c] ----
__global__ __launch_bounds__(256) void k_f12(const unsigned short* __restrict__ WhT,
                                             const void* __restrict__ avec,
                                             const int* __restrict__ flag,
                                             float* __restrict__ f1, float* __restrict__ f2,
                                             int DC) {
  int isbf = *flag;
  int head = blockIdx.y;
  int r = blockIdx.x * 256 + threadIdx.x;
  const unsigned short* wt = WhT + (size_t)head * DC * NN;
  size_t abase = (size_t)head * 2 * DC;
  float s1 = 0.f, s2 = 0.f;
  for (int c = 0; c < DC; c++) {
    float wv = bf2f(wt[(size_t)c * NN + r]);
    s1 += wv * ldin(avec, abase + c, isbf);
    s2 += wv * ldin(avec, abase + DC + c, isbf);
  }
  f1[head * NN + r] = s1;
  f2[head * NN + r] = s2;
}

// ---- fused masked-softmax attention + aggregate + ELU ----
// block: 64 rows x DCOL cols, BK=32, ping-pong P tile in LDS, MFMA 16x16x32
template<int DCOL>
__global__ __launch_bounds__(256) void k_attn(const unsigned* __restrict__ maskw,
                                              const float* __restrict__ f1g,
                                              const float* __restrict__ f2g,
                                              const unsigned short* __restrict__ WhTg,
                                              void* __restrict__ outg,
                                              long outHeadOff, int outRowStride,
                                              const int* __restrict__ flag, int finalOut) {
  constexpr int NCT = DCOL / 64;                  // col-tiles per wave
  __shared__ __align__(16) float f2s[NN];         // 12 KB
  __shared__ __align__(16) unsigned msk[64 * NWORD]; // 24 KB
  __shared__ __align__(16) float f1s[64];
  __shared__ __align__(16) float dinv[64];
  __shared__ __align__(16) unsigned short Pl[2][64 * 40]; // ping-pong, 80B rows

  int f32out = finalOut && (*flag == 0);
  int head = blockIdx.y;
  int rowbase = blockIdx.x * 64;
  const float* f1p = f1g + head * NN;
  const float* f2p = f2g + head * NN;
  const unsigned short* WhT = WhTg + (size_t)head * DCOL * NN;

  int t = threadIdx.x;
  for (int i = t; i < NN; i += 256) f2s[i] = f2p[i];
  for (int i = t; i < 64 * NWORD; i += 256) msk[i] = maskw[(size_t)rowbase * NWORD + i];
  if (t < 64) f1s[t] = f1p[rowbase + t];
  __syncthreads();

  int lane = t & 63, w = t >> 6;
  int q = lane >> 4, l = lane & 15;
  int r = t >> 2;            // 0..63: this thread's P row
  int jq = t & 3;            // 8-j group within BK=32
  int j0off = jq * 8;
  float f1r = f1s[r];
  const unsigned* mrow = &msk[r * NWORD];
  int colbase = w * 16 * NCT;

  float4v acc[4][NCT];
#pragma unroll
  for (int rt = 0; rt < 4; rt++)
#pragma unroll
    for (int ct = 0; ct < NCT; ct++) { float4v z = {0.f, 0.f, 0.f, 0.f}; acc[rt][ct] = z; }
  float dsum = 0.f;

  int pb = 0;
  for (int jb = 0; jb < NN; jb += 32) {
    unsigned mw = mrow[jb >> 5] >> j0off;
    float4v fa = *(const float4v*)(&f2s[jb + j0off]);
    float4v fb = *(const float4v*)(&f2s[jb + j0off + 4]);
    ushort8v pk;
#pragma unroll
    for (int i = 0; i < 8; i++) {
      float e = f1r + (i < 4 ? fa[i] : fb[i - 4]);
      e = fmaxf(e, 0.2f * e);                     // LeakyReLU(0.2)
      e = fminf(e, 30.f);                         // hard guard: no Inf ever
      float pv = ((mw >> i) & 1u) ? __expf(e) : 0.f;
      dsum += pv;
      pk[i] = f2bf(pv);
    }
    *(ushort8v*)(&Pl[pb][r * 40 + j0off]) = pk;
    __syncthreads();                              // P visible; prev reads of this buf done last iter

    short8 af[4], bfr[NCT];
#pragma unroll
    for (int rt = 0; rt < 4; rt++)
      af[rt] = *(const short8*)(&Pl[pb][(rt * 16 + l) * 40 + q * 8]);
#pragma unroll
    for (int ct = 0; ct < NCT; ct++)
      bfr[ct] = *(const short8*)(WhT + (size_t)(colbase + ct * 16 + l) * NN + jb + q * 8);
#pragma unroll
    for (int rt = 0; rt < 4; rt++)
#pragma unroll
      for (int ct = 0; ct < NCT; ct++)
        acc[rt][ct] = __builtin_amdgcn_mfma_f32_16x16x32_bf16(af[rt], bfr[ct], acc[rt][ct], 0, 0, 0);
    pb ^= 1;
  }

  // denominator: each row owned by 4 consecutive lanes (jq 0..3)
  dsum += __shfl_xor(dsum, 1, 64);
  dsum += __shfl_xor(dsum, 2, 64);
  if (jq == 0) dinv[r] = dsum > 0.f ? 1.f / dsum : 0.f;
  __syncthreads();

#pragma unroll
  for (int rt = 0; rt < 4; rt++)
#pragma unroll
    for (int ct = 0; ct < NCT; ct++) {
#pragma unroll
      for (int reg = 0; reg < 4; reg++) {
        int lr = rt * 16 + q * 4 + reg;
        int c = colbase + ct * 16 + l;
        float v = acc[rt][ct][reg] * dinv[lr];
        v = v > 0.f ? v : expm1f(v);              // ELU
        size_t idx = (size_t)head * outHeadOff + (size_t)(rowbase + lr) * outRowStride + c;
        if (f32out) ((float*)outg)[idx] = v;
        else ((unsigned short*)outg)[idx] = f2bf(v);
      }
    }
}

extern "C" void kernel_launch(void* const* d_in, const int* in_sizes, int n_in,
                              void* d_out, int out_size, void* d_ws, size_t ws_size,
                              hipStream_t stream) {
  const void* x     = d_in[0];
  const void* adj   = d_in[1];
  const int*  obs   = (const int*)d_in[2];
  // d_in[3] s_mat unused (method='base')
  const void* theta = d_in[4];
  const void* W0    = d_in[5];
  const void* a0    = d_in[6];
  const void* W1    = d_in[7];
  const void* a1    = d_in[8];
  const void* Wo    = d_in[9];
  const void* ao    = d_in[10];

  char* ws = (char*)d_ws;
  size_t off = 0;
  auto alloc = [&](size_t bytes) { void* p = ws + off; off += (bytes + 255) & ~(size_t)255; return p; };
  int*            flag  = (int*)alloc(4);
  unsigned*       maskw = (unsigned*)alloc((size_t)NN * NWORD * 4);
  unsigned short* h_bf  = (unsigned short*)alloc((size_t)NN * 256 * 2);
  unsigned short* WhT   = (unsigned short*)alloc((size_t)HH * 128 * NN * 2);
  float*          f1    = (float*)alloc((size_t)HH * NN * 4);
  float*          f2    = (float*)alloc((size_t)HH * NN * 4);
  unsigned short* h0    = (unsigned short*)alloc((size_t)HH * NN * 128 * 2);
  unsigned short* hc    = (unsigned short*)alloc((size_t)NN * 1024 * 2);
  unsigned short* W0T   = (unsigned short*)alloc((size_t)HH * 128 * 256 * 2);
  unsigned short* W1T   = (unsigned short*)alloc((size_t)HH * 128 * 128 * 2);
  unsigned short* WoT   = (unsigned short*)alloc((size_t)64 * 1024 * 2);
  unsigned short* WhoT  = (unsigned short*)alloc((size_t)64 * NN * 2);
  float*          fo1   = (float*)alloc((size_t)NN * 4);
  float*          fo2   = (float*)alloc((size_t)NN * 4);

  k_detect<<<1, 256, 0, stream>>>((const unsigned*)adj, flag);
  k_mask<<<dim3(12, NN), 256, 0, stream>>>(adj, flag, maskw);
  k_merge<<<dim3(NN * 256 / 256), 256, 0, stream>>>(x, obs, theta, flag, h_bf);
  k_transpose<<<dim3(8, 16, HH), 256, 0, stream>>>(W0, flag, W0T, 256, 128);
  k_transpose<<<dim3(8, 8, HH), 256, 0, stream>>>(W1, flag, W1T, 128, 128);
  k_transpose<<<dim3(4, 64, 1), 256, 0, stream>>>(Wo, flag, WoT, 1024, 64);

  // ---- layer 0 ----
  k_gemm<256, 2><<<dim3(NN / 64, HH), 256, 0, stream>>>(h_bf, W0T, WhT,
                                                        0, 128 * 256, (long)128 * NN);
  k_f12<<<dim3(NN / 256, HH), 256, 0, stream>>>(WhT, a0, flag, f1, f2, 128);
  k_attn<128><<<dim3(NN / 64, HH), 256, 0, stream>>>(maskw, f1, f2, WhT, (void*)h0,
                                                     (long)NN * 128, 128, flag, 0);
  // ---- layer 1 ----
  k_gemm<128, 2><<<dim3(NN / 64, HH), 256, 0, stream>>>(h0, W1T, WhT,
                                                        (long)NN * 128, 128 * 128, (long)128 * NN);
  k_f12<<<dim3(NN / 256, HH), 256, 0, stream>>>(WhT, a1, flag, f1, f2, 128);
  k_attn<128><<<dim3(NN / 64, HH), 256, 0, stream>>>(maskw, f1, f2, WhT, (void*)hc,
                                                     128, 1024, flag, 0);
  // ---- output layer ----
  k_gemm<1024, 1><<<dim3(NN / 64, 1), 256, 0, stream>>>(hc, WoT, WhoT, 0, 0, 0);
  k_f12<<<dim3(NN / 256, 1), 256, 0, stream>>>(WhoT, ao, flag, fo1, fo2, 64);
  k_attn<64><<<dim3(NN / 64, 1), 256, 0, stream>>>(maskw, fo1, fo2, WhoT, d_out, 0, 64, flag, 1);
}

// Round 3
// 463.865 us; speedup vs baseline: 1.2117x; 1.2117x over previous
//
#include <hip/hip_runtime.h>

#define NN 3072
#define NWORD 96   // u32 mask words per row
#define HH 8

typedef short short8 __attribute__((ext_vector_type(8)));
typedef float float4v __attribute__((ext_vector_type(4)));
typedef unsigned short ushort4v __attribute__((ext_vector_type(4)));

__device__ __forceinline__ float bf2f(unsigned short u) {
  union { unsigned u; float f; } v; v.u = ((unsigned)u) << 16; return v.f;
}
__device__ __forceinline__ unsigned short f2bf(float f) {
  union { float f; unsigned u; } v; v.f = f;
  unsigned r = v.u + 0x7fffu + ((v.u >> 16) & 1u);
  return (unsigned short)(r >> 16);
}
// flag==1 -> buffers are bf16; flag==0 -> fp32
__device__ __forceinline__ float ldin(const void* p, size_t i, int isbf) {
  return isbf ? bf2f(((const unsigned short*)p)[i]) : ((const float*)p)[i];
}

// ---- dtype detect: adj is exactly {0.0,1.0}. fp32 words have low16==0 always. ----
__global__ __launch_bounds__(256) void k_detect(const unsigned* __restrict__ aw,
                                                int* __restrict__ flag) {
  __shared__ int s;
  if (threadIdx.x == 0) s = 0;
  __syncthreads();
  int any = 0;
  for (int i = threadIdx.x; i < 16384; i += 256)
    any |= ((aw[i] & 0xFFFFu) != 0u);
  if (any) s = 1;   // benign race
  __syncthreads();
  if (threadIdx.x == 0) *flag = s;
}

// ---- build bitmask from adj ----
__global__ __launch_bounds__(256) void k_mask(const void* __restrict__ adj,
                                              const int* __restrict__ flag,
                                              unsigned* __restrict__ maskw) {
  int isbf = *flag;
  int row = blockIdx.y;
  int j = blockIdx.x * 256 + threadIdx.x;
  bool pred = ldin(adj, (size_t)row * NN + j, isbf) != 0.f;
  unsigned long long b = __ballot(pred);
  int lane = threadIdx.x & 63;
  int word = row * NWORD + blockIdx.x * 8 + (threadIdx.x >> 6) * 2;
  if (lane == 0) maskw[word] = (unsigned)b;
  else if (lane == 32) maskw[word + 1] = (unsigned)(b >> 32);
}

// ---- mergeState: h = x + (obs==1) * theta ----
__global__ __launch_bounds__(256) void k_merge(const void* __restrict__ x,
                                               const int* __restrict__ obs,
                                               const void* __restrict__ theta,
                                               const int* __restrict__ flag,
                                               unsigned short* __restrict__ h) {
  int isbf = *flag;
  int i = blockIdx.x * 256 + threadIdx.x;
  int row = i >> 8, c = i & 255;
  float v = ldin(x, i, isbf);
  if (obs[row] == 1) v += ldin(theta, c, isbf);
  h[i] = f2bf(v);
}

// ---- batched 16x16 LDS transpose: in[b][R][C] -> out[b][C][R] (out bf16) ----
__global__ __launch_bounds__(256) void k_transpose(const void* __restrict__ in,
                                                   const int* __restrict__ flag,
                                                   unsigned short* __restrict__ out,
                                                   int R, int C) {
  __shared__ __align__(16) unsigned short tile[16][17];
  int isbf = *flag;
  int b = blockIdx.z;
  size_t base = (size_t)b * R * C;
  unsigned short* pout = out + base;
  int r0 = blockIdx.y * 16, c0 = blockIdx.x * 16;
  int tc = threadIdx.x & 15, tr = threadIdx.x >> 4;
  tile[tr][tc] = f2bf(ldin(in, base + (size_t)(r0 + tr) * C + (c0 + tc), isbf));
  __syncthreads();
  pout[(size_t)(c0 + tr) * R + (r0 + tc)] = tile[tc][tr];
}

// ---- GEMM: CT[n][m] = sum_k A[m][k] * WT[n][k], all bf16, M=3072 ----
// block: ROWS rows x (64*NCT) cols, 4 waves, MFMA 16x16x32
template<int K, int NCT, int ROWS>
__global__ __launch_bounds__(256) void k_gemm(const unsigned short* __restrict__ A,
                                              const unsigned short* __restrict__ WT,
                                              unsigned short* __restrict__ CT,
                                              long aOff, long wOff, long cOff) {
  constexpr int RT = ROWS / 16;
  int head = blockIdx.y;
  A += (size_t)head * aOff; WT += (size_t)head * wOff; CT += (size_t)head * cOff;
  int rowbase = blockIdx.x * ROWS;
  int t = threadIdx.x;
  int w = t >> 6, lane = t & 63;
  int q = lane >> 4, l = lane & 15;
  int colbase = w * 16 * NCT;
  float4v acc[RT][NCT];
#pragma unroll
  for (int rt = 0; rt < RT; rt++)
#pragma unroll
    for (int ct = 0; ct < NCT; ct++) { float4v z = {0.f, 0.f, 0.f, 0.f}; acc[rt][ct] = z; }

  for (int kb = 0; kb < K; kb += 32) {
    short8 af[RT], bfr[NCT];
#pragma unroll
    for (int rt = 0; rt < RT; rt++)
      af[rt] = *(const short8*)(A + (size_t)(rowbase + rt * 16 + l) * K + kb + q * 8);
#pragma unroll
    for (int ct = 0; ct < NCT; ct++)
      bfr[ct] = *(const short8*)(WT + (size_t)(colbase + ct * 16 + l) * K + kb + q * 8);
#pragma unroll
    for (int rt = 0; rt < RT; rt++)
#pragma unroll
      for (int ct = 0; ct < NCT; ct++)
        acc[rt][ct] = __builtin_amdgcn_mfma_f32_16x16x32_bf16(af[rt], bfr[ct], acc[rt][ct], 0, 0, 0);
  }
#pragma unroll
  for (int rt = 0; rt < RT; rt++)
#pragma unroll
    for (int ct = 0; ct < NCT; ct++) {
      int r = rowbase + rt * 16 + q * 4;          // C/D: row = quad*4 + reg
      int n = colbase + ct * 16 + l;              // C/D: col = lane&15
      ushort4v u;
      u.x = f2bf(acc[rt][ct].x); u.y = f2bf(acc[rt][ct].y);
      u.z = f2bf(acc[rt][ct].z); u.w = f2bf(acc[rt][ct].w);
      *(ushort4v*)(CT + (size_t)n * NN + r) = u;
    }
}

// ---- f1/f2 GEMV from WhT: f1[r]=sum_c WhT[c][r]*a[c], f2 with a[DC+c] ----
__global__ __launch_bounds__(256) void k_f12(const unsigned short* __restrict__ WhT,
                                             const void* __restrict__ avec,
                                             const int* __restrict__ flag,
                                             float* __restrict__ f1, float* __restrict__ f2,
                                             int DC) {
  int isbf = *flag;
  int head = blockIdx.y;
  int r = blockIdx.x * 256 + threadIdx.x;
  const unsigned short* wt = WhT + (size_t)head * DC * NN;
  size_t abase = (size_t)head * 2 * DC;
  float s1 = 0.f, s2 = 0.f;
#pragma unroll 8
  for (int c = 0; c < DC; c++) {
    float wv = bf2f(wt[(size_t)c * NN + r]);
    s1 += wv * ldin(avec, abase + c, isbf);
    s2 += wv * ldin(avec, abase + DC + c, isbf);
  }
  f1[head * NN + r] = s1;
  f2[head * NN + r] = s2;
}

// ---- attention partial: barrier-free, LDS-free ----
// One wave = 32 rows x DCOL cols x j-range [js*NN/S, (js+1)*NN/S).
// Each lane computes the exact 8 P values of its MFMA A-fragment in registers
// (A[m=lane&15][k=quad*8+i]); partial numerator (fp32) + denominator to ws.
template<int DCOL, int S>
__global__ __launch_bounds__(256, 3) void k_attn_part(
    const unsigned* __restrict__ maskw,
    const float* __restrict__ f1g, const float* __restrict__ f2g,
    const unsigned short* __restrict__ WhTg,
    float* __restrict__ pnum, float* __restrict__ pden) {
  constexpr int NCT = DCOL / 16;
  constexpr int JCH = NN / S;
  int NH = gridDim.z;
  int head = blockIdx.z, js = blockIdx.y;
  int w = threadIdx.x >> 6, lane = threadIdx.x & 63;
  int q = lane >> 4, l = lane & 15;
  int rowbase = (blockIdx.x * 4 + w) * 32;
  const float* f1p = f1g + head * NN;
  const float* f2p = f2g + head * NN;
  const unsigned short* WhT = WhTg + (size_t)head * DCOL * NN;
  float f1r0 = f1p[rowbase + l];
  float f1r1 = f1p[rowbase + 16 + l];
  const unsigned* mrow0 = maskw + (size_t)(rowbase + l) * NWORD;
  const unsigned* mrow1 = maskw + (size_t)(rowbase + 16 + l) * NWORD;

  float4v acc[2][NCT];
#pragma unroll
  for (int rt = 0; rt < 2; rt++)
#pragma unroll
    for (int ct = 0; ct < NCT; ct++) { float4v z = {0.f, 0.f, 0.f, 0.f}; acc[rt][ct] = z; }
  float ds0 = 0.f, ds1 = 0.f;

  int j0 = js * JCH;
  for (int jb = j0; jb < j0 + JCH; jb += 32) {
    unsigned w0 = mrow0[jb >> 5] >> (q * 8);
    unsigned w1 = mrow1[jb >> 5] >> (q * 8);
    float4v fa = *(const float4v*)(f2p + jb + q * 8);
    float4v fb = *(const float4v*)(f2p + jb + q * 8 + 4);
    short8 af0, af1;
#pragma unroll
    for (int i = 0; i < 8; i++) {
      float fv = (i < 4) ? fa[i] : fb[i - 4];
      float e0 = f1r0 + fv;
      e0 = fminf(fmaxf(e0, 0.2f * e0), 30.f);      // LeakyReLU + overflow guard
      float p0 = ((w0 >> i) & 1u) ? __expf(e0) : 0.f;
      ds0 += p0; af0[i] = (short)f2bf(p0);
      float e1 = f1r1 + fv;
      e1 = fminf(fmaxf(e1, 0.2f * e1), 30.f);
      float p1 = ((w1 >> i) & 1u) ? __expf(e1) : 0.f;
      ds1 += p1; af1[i] = (short)f2bf(p1);
    }
#pragma unroll
    for (int ct = 0; ct < NCT; ct++) {
      short8 bfr = *(const short8*)(WhT + (size_t)(ct * 16 + l) * NN + jb + q * 8);
      acc[0][ct] = __builtin_amdgcn_mfma_f32_16x16x32_bf16(af0, bfr, acc[0][ct], 0, 0, 0);
      acc[1][ct] = __builtin_amdgcn_mfma_f32_16x16x32_bf16(af1, bfr, acc[1][ct], 0, 0, 0);
    }
  }

  // denominator: sum over q for each row (lanes l, l+16, l+32, l+48)
  ds0 += __shfl_xor(ds0, 16, 64); ds0 += __shfl_xor(ds0, 32, 64);
  ds1 += __shfl_xor(ds1, 16, 64); ds1 += __shfl_xor(ds1, 32, 64);
  size_t slab = (size_t)(js * NH + head);
  if (q == 0) {
    pden[slab * NN + rowbase + l] = ds0;
    pden[slab * NN + rowbase + 16 + l] = ds1;
  }
#pragma unroll
  for (int rt = 0; rt < 2; rt++)
#pragma unroll
    for (int ct = 0; ct < NCT; ct++)
#pragma unroll
      for (int reg = 0; reg < 4; reg++) {
        int row = rowbase + rt * 16 + q * 4 + reg;
        int col = ct * 16 + l;
        pnum[(slab * NN + row) * DCOL + col] = acc[rt][ct][reg];
      }
}

// ---- combine partials: divide, ELU, store in layer-specific layout ----
template<int DCOL, int S>
__global__ __launch_bounds__(256) void k_attn_reduce(
    const float* __restrict__ pnum, const float* __restrict__ pden,
    void* __restrict__ outg, long outHeadOff, int outRowStride, int NH,
    const int* __restrict__ flag, int finalOut) {
  int tid = blockIdx.x * 256 + threadIdx.x;
  int col = tid & (DCOL - 1);
  int row = (tid / DCOL) % NN;
  int h = tid / (DCOL * NN);
  float sn = 0.f, sd = 0.f;
#pragma unroll
  for (int js = 0; js < S; js++) {
    size_t slab = (size_t)(js * NH + h);
    sn += pnum[(slab * NN + row) * DCOL + col];
    sd += pden[slab * NN + row];
  }
  float v = sd > 0.f ? sn / sd : 0.f;
  v = v > 0.f ? v : expm1f(v);                    // ELU
  size_t idx = (size_t)h * outHeadOff + (size_t)row * outRowStride + col;
  if (finalOut && *flag == 0) ((float*)outg)[idx] = v;
  else ((unsigned short*)outg)[idx] = f2bf(v);
}

extern "C" void kernel_launch(void* const* d_in, const int* in_sizes, int n_in,
                              void* d_out, int out_size, void* d_ws, size_t ws_size,
                              hipStream_t stream) {
  const void* x     = d_in[0];
  const void* adj   = d_in[1];
  const int*  obs   = (const int*)d_in[2];
  // d_in[3] s_mat unused (method='base')
  const void* theta = d_in[4];
  const void* W0    = d_in[5];
  const void* a0    = d_in[6];
  const void* W1    = d_in[7];
  const void* a1    = d_in[8];
  const void* Wo    = d_in[9];
  const void* ao    = d_in[10];

  char* ws = (char*)d_ws;
  size_t off = 0;
  auto alloc = [&](size_t bytes) { void* p = ws + off; off += (bytes + 255) & ~(size_t)255; return p; };
  int*            flag  = (int*)alloc(4);
  unsigned*       maskw = (unsigned*)alloc((size_t)NN * NWORD * 4);
  unsigned short* h_bf  = (unsigned short*)alloc((size_t)NN * 256 * 2);
  unsigned short* WhT   = (unsigned short*)alloc((size_t)HH * 128 * NN * 2);
  float*          f1    = (float*)alloc((size_t)HH * NN * 4);
  float*          f2    = (float*)alloc((size_t)HH * NN * 4);
  unsigned short* h0    = (unsigned short*)alloc((size_t)HH * NN * 128 * 2);
  unsigned short* hc    = (unsigned short*)alloc((size_t)NN * 1024 * 2);
  unsigned short* W0T   = (unsigned short*)alloc((size_t)HH * 128 * 256 * 2);
  unsigned short* W1T   = (unsigned short*)alloc((size_t)HH * 128 * 128 * 2);
  unsigned short* WoT   = (unsigned short*)alloc((size_t)64 * 1024 * 2);
  unsigned short* WhoT  = (unsigned short*)alloc((size_t)64 * NN * 2);
  float*          fo1   = (float*)alloc((size_t)NN * 4);
  float*          fo2   = (float*)alloc((size_t)NN * 4);

  // partial buffers sized by split factor S, bounded by ws_size
  size_t fixedEnd = off;
  auto needBytes = [&](int s) {
    return fixedEnd + (size_t)s * HH * NN * 128 * 4 + (size_t)s * HH * NN * 4 + 8192;
  };
  int S = (needBytes(4) <= ws_size) ? 4 : (needBytes(2) <= ws_size) ? 2 : 1;
  float* pnum = (float*)alloc((size_t)S * HH * NN * 128 * 4);
  float* pden = (float*)alloc((size_t)S * HH * NN * 4);
  int So = (S * HH >= 8) ? 8 : S;   // output layer split (buffer reuse bound)

  k_detect<<<1, 256, 0, stream>>>((const unsigned*)adj, flag);
  k_mask<<<dim3(12, NN), 256, 0, stream>>>(adj, flag, maskw);
  k_merge<<<dim3(NN), 256, 0, stream>>>(x, obs, theta, flag, h_bf);
  k_transpose<<<dim3(8, 16, HH), 256, 0, stream>>>(W0, flag, W0T, 256, 128);
  k_transpose<<<dim3(8, 8, HH), 256, 0, stream>>>(W1, flag, W1T, 128, 128);
  k_transpose<<<dim3(4, 64, 1), 256, 0, stream>>>(Wo, flag, WoT, 1024, 64);

  // ---- layer 0 ----
  k_gemm<256, 2, 32><<<dim3(NN / 32, HH), 256, 0, stream>>>(h_bf, W0T, WhT,
                                                            0, 128 * 256, (long)128 * NN);
  k_f12<<<dim3(NN / 256, HH), 256, 0, stream>>>(WhT, a0, flag, f1, f2, 128);
  switch (S) {
    case 4:
      k_attn_part<128, 4><<<dim3(24, 4, HH), 256, 0, stream>>>(maskw, f1, f2, WhT, pnum, pden);
      k_attn_reduce<128, 4><<<dim3(HH * NN * 128 / 256), 256, 0, stream>>>(pnum, pden, h0, (long)NN * 128, 128, HH, flag, 0);
      break;
    case 2:
      k_attn_part<128, 2><<<dim3(24, 2, HH), 256, 0, stream>>>(maskw, f1, f2, WhT, pnum, pden);
      k_attn_reduce<128, 2><<<dim3(HH * NN * 128 / 256), 256, 0, stream>>>(pnum, pden, h0, (long)NN * 128, 128, HH, flag, 0);
      break;
    default:
      k_attn_part<128, 1><<<dim3(24, 1, HH), 256, 0, stream>>>(maskw, f1, f2, WhT, pnum, pden);
      k_attn_reduce<128, 1><<<dim3(HH * NN * 128 / 256), 256, 0, stream>>>(pnum, pden, h0, (long)NN * 128, 128, HH, flag, 0);
  }
  // ---- layer 1 ----
  k_gemm<128, 2, 32><<<dim3(NN / 32, HH), 256, 0, stream>>>(h0, W1T, WhT,
                                                            (long)NN * 128, 128 * 128, (long)128 * NN);
  k_f12<<<dim3(NN / 256, HH), 256, 0, stream>>>(WhT, a1, flag, f1, f2, 128);
  switch (S) {
    case 4:
      k_attn_part<128, 4><<<dim3(24, 4, HH), 256, 0, stream>>>(maskw, f1, f2, WhT, pnum, pden);
      k_attn_reduce<128, 4><<<dim3(HH * NN * 128 / 256), 256, 0, stream>>>(pnum, pden, hc, 128, 1024, HH, flag, 0);
      break;
    case 2:
      k_attn_part<128, 2><<<dim3(24, 2, HH), 256, 0, stream>>>(maskw, f1, f2, WhT, pnum, pden);
      k_attn_reduce<128, 2><<<dim3(HH * NN * 128 / 256), 256, 0, stream>>>(pnum, pden, hc, 128, 1024, HH, flag, 0);
      break;
    default:
      k_attn_part<128, 1><<<dim3(24, 1, HH), 256, 0, stream>>>(maskw, f1, f2, WhT, pnum, pden);
      k_attn_reduce<128, 1><<<dim3(HH * NN * 128 / 256), 256, 0, stream>>>(pnum, pden, hc, 128, 1024, HH, flag, 0);
  }
  // ---- output layer ----
  k_gemm<1024, 1, 16><<<dim3(NN / 16, 1), 256, 0, stream>>>(hc, WoT, WhoT, 0, 0, 0);
  k_f12<<<dim3(NN / 256, 1), 256, 0, stream>>>(WhoT, ao, flag, fo1, fo2, 64);
  if (So == 8) {
    k_attn_part<64, 8><<<dim3(24, 8, 1), 256, 0, stream>>>(maskw, fo1, fo2, WhoT, pnum, pden);
    k_attn_reduce<64, 8><<<dim3(NN * 64 / 256), 256, 0, stream>>>(pnum, pden, d_out, 0, 64, 1, flag, 1);
  } else if (So == 2) {
    k_attn_part<64, 2><<<dim3(24, 2, 1), 256, 0, stream>>>(maskw, fo1, fo2, WhoT, pnum, pden);
    k_attn_reduce<64, 2><<<dim3(NN * 64 / 256), 256, 0, stream>>>(pnum, pden, d_out, 0, 64, 1, flag, 1);
  } else {
    k_attn_part<64, 1><<<dim3(24, 1, 1), 256, 0, stream>>>(maskw, fo1, fo2, WhoT, pnum, pden);
    k_attn_reduce<64, 1><<<dim3(NN * 64 / 256), 256, 0, stream>>>(pnum, pden, d_out, 0, 64, 1, flag, 1);
  }
}